// Round 6
// baseline (251.627 us; speedup 1.0000x reference)
//
#include <hip/hip_runtime.h>
#include <math.h>
#include <stdint.h>

// Problem constants (B=4, S=4096, D=2048, E=64, K=8)
#define NTOK   16384      // B*S
#define DDIM   2048
#define NE     64
#define TOPK   8

#define THREADS 256       // 4 waves
#define TOKPB   16        // 1024 blocks -> 4 resident/CU -> 4 barrier domains
#define BK      64        // K-chunk per stage
#define NCHUNK  (DDIM / BK)   // 32

// float4 slots: x tile [16 t][16 k4] (4 KiB), W tile [64 k][16 e4] (16 KiB)
#define XSLOTS   (TOKPB * (BK / 4))   // 256
#define WSLOTS   (BK * (NE / 4))      // 1024
#define BUFSLOTS (XSLOTS + WSLOTS)    // 1280 (20 KiB)
#define SMEMF4   (2 * BUFSLOTS)       // 40 KiB -> 4 blocks/CU (4*40960 = 160 KiB)

// Async global->LDS DMA, 16 B per lane; LDS dest = wave-uniform base +
// lane*16 (m104/m108). All layouts linear both sides (proven R1 idioms).
__device__ __forceinline__ void gl_lds16(const void* g, void* l) {
    __builtin_amdgcn_global_load_lds(
        (const __attribute__((address_space(1))) void*)(uintptr_t)g,
        (__attribute__((address_space(3))) void*)(uintptr_t)l,
        16, 0, 0);
}

__global__ __launch_bounds__(THREADS, 4) void gate_kernel(
    const float* __restrict__ x, const float* __restrict__ W,
    const float* __restrict__ b, float* __restrict__ out)
{
    __shared__ float4 smem[SMEMF4];   // 40 KiB

    const int tid  = threadIdx.x;
    const int wave = tid >> 6;
    const int lane = tid & 63;
    const int ks   = tid >> 4;        // k4 slice 0..15 (4 k per chunk each)
    const int tg   = (tid >> 3) & 1;  // token group (8 tokens each)
    const int eg   = tid & 7;         // expert octet (8 experts each)
    const int tok0 = blockIdx.x * TOKPB;

    // ---- staging sources (linear, fully coalesced) ----
    // x tile slot s = wave*64 + lane: t = s>>4, k4 = s&15
    //   -> 16 consecutive lanes cover one token row's 256 B.
    const float* gx = x + (size_t)(tok0 + wave * 4 + (lane >> 4)) * DDIM
                        + (lane & 15) * 4;
    // W tile slot s = wave*256 + q*64 + lane: [k][e4] row-major == global.
    const float* gw = W + (size_t)(wave * 256 + lane) * 4;

    auto stage = [&](int c) {
        float4* Bf = &smem[(c & 1) * BUFSLOTS];
        gl_lds16(gx + c * BK, &Bf[wave * 64]);                    // x: 1 KiB/wave
        const float* wsrc = gw + (size_t)c * (BK * NE);
#pragma unroll
        for (int q = 0; q < 4; ++q)
            gl_lds16(wsrc + q * 256, &Bf[XSLOTS + wave * 256 + q * 64]);
    };

    float acc[8][8];
#pragma unroll
    for (int i = 0; i < 8; ++i)
#pragma unroll
        for (int j = 0; j < 8; ++j) acc[i][j] = 0.f;

    // Per thread per chunk: 8 x-b128 + 8 W-b128 feed 256 FMAs (R1 ratio).
    // Banks: x slot (tg*8+i)*16+ks -> quad ks&7, eg broadcast, tg 2-way (free).
    // W paired reads eg*2/eg*2+1 -> R1-measured ~0 conflicts.
    stage(0);
#pragma unroll 1
    for (int c = 0; c < NCHUNK; ++c) {
        __syncthreads();                   // stage(c) drained; other buf free
        if (c + 1 < NCHUNK) stage(c + 1);  // lands during compute
        const float4* BX = &smem[(c & 1) * BUFSLOTS];
        const float4* BW = BX + XSLOTS;
        __builtin_amdgcn_s_setprio(1);
        float4 xv[8];
#pragma unroll
        for (int i = 0; i < 8; ++i)
            xv[i] = BX[(tg * 8 + i) * 16 + ks];
#pragma unroll
        for (int kk = 0; kk < 4; ++kk) {
            const int k = ks * 4 + kk;
            const float4 wa = BW[k * 16 + eg * 2];
            const float4 wb = BW[k * 16 + eg * 2 + 1];
            const float ws[8] = {wa.x, wa.y, wa.z, wa.w,
                                 wb.x, wb.y, wb.z, wb.w};
#pragma unroll
            for (int i = 0; i < 8; ++i) {
                const float xs = ((const float*)&xv[i])[kk];
#pragma unroll
                for (int j = 0; j < 8; ++j)
                    acc[i][j] = fmaf(xs, ws[j], acc[i][j]);
            }
        }
        __builtin_amdgcn_s_setprio(0);
    }
    __syncthreads();   // all compute done; smem reusable for epilogue

    // ---- reduce over the wave's 4 ks-slices: lanes l, l^16, l^32, l^48
    // share (tg,eg) (xor on lane bits 4,5 preserves bits 0..3) ----
#pragma unroll
    for (int i = 0; i < 8; ++i)
#pragma unroll
        for (int j = 0; j < 8; ++j) {
            acc[i][j] += __shfl_xor(acc[i][j], 16);
            acc[i][j] += __shfl_xor(acc[i][j], 32);
        }

    // ---- cross-wave partials: [4 w][16 p][17 f4] = 1088 f4 (17 KiB) ----
    float4* part4 = smem;
    const int p = lane & 15;              // = tg*8 + eg
    if (lane < 16) {
        float4* dst = part4 + (wave * 16 + p) * 17;
#pragma unroll
        for (int i = 0; i < 8; ++i) {
            dst[i * 2]     = make_float4(acc[i][0], acc[i][1], acc[i][2], acc[i][3]);
            dst[i * 2 + 1] = make_float4(acc[i][4], acc[i][5], acc[i][6], acc[i][7]);
        }
    }
    __syncthreads();

    float* out_g   = out;                           // [16384][8]
    float* out_idx = out + (size_t)NTOK * TOPK;     // [16384][8] (as float)
    float* out_s   = out + (size_t)NTOK * TOPK * 2; // [16384][64]

    // ---- collect 4 wave-partials, bias, sigmoid (all 256 threads) ----
    const int t  = tid >> 4;              // token 0..15
    const int e4 = tid & 15;              // expert quad
    {
        const int cp = (t >> 3) * 8 + (e4 >> 1);   // partial p = tg*8 + eg
        const int cf = (t & 7) * 2 + (e4 & 1);     // f4 index = i*2 + half
        float sx = 0.f, sy = 0.f, sz = 0.f, sw = 0.f;
#pragma unroll
        for (int w = 0; w < 4; ++w) {
            const float4 v = part4[(w * 16 + cp) * 17 + cf];
            sx += v.x; sy += v.y; sz += v.z; sw += v.w;
        }
        const float4 bv = *(const float4*)(b + e4 * 4);
        float4 sg;
        sg.x = 1.f / (1.f + expf(-(sx + bv.x)));
        sg.y = 1.f / (1.f + expf(-(sy + bv.y)));
        sg.z = 1.f / (1.f + expf(-(sz + bv.z)));
        sg.w = 1.f / (1.f + expf(-(sw + bv.w)));
        __syncthreads();   // all partial reads done before score overwrite
        float4* sc4 = smem;               // scores [16 t][17 f4]
        sc4[t * 17 + e4] = sg;
        *(float4*)(out_s + (size_t)(tok0 + t) * NE + e4 * 4) = sg;  // coalesced
    }
    __syncthreads();

    // ---- parallel top-8: 8 lanes per token, butterfly argmax with
    // lowest-index tie-break (matches jax.lax.top_k). Proven in R1-R3. ----
    if (tid < 128) {
        const float4* sc4 = (const float4*)smem;
        const int tt = tid >> 3, lg = tid & 7;
        const float4 a0 = sc4[tt * 17 + lg * 2];
        const float4 a1 = sc4[tt * 17 + lg * 2 + 1];
        float s[8] = {a0.x, a0.y, a0.z, a0.w, a1.x, a1.y, a1.z, a1.w};
        float vsel = 0.f; int esel = 0; float ssum = 0.f;
#pragma unroll
        for (int j = 0; j < TOPK; ++j) {
            // local max over remaining 8 (ascending scan, strict > -> lowest idx)
            float bvv = s[0]; int be = 0;
#pragma unroll
            for (int m = 1; m < 8; ++m)
                if (s[m] > bvv) { bvv = s[m]; be = m; }
            float v = bvv; int ec = lg * 8 + be;
#pragma unroll
            for (int d = 1; d < 8; d <<= 1) {
                const float ov = __shfl_xor(v, d);
                const int   oe = __shfl_xor(ec, d);
                if (ov > v || (ov == v && oe < ec)) { v = ov; ec = oe; }
            }
            ssum += v;
            if (lg == j) { vsel = v; esel = ec; }
            // remove winner (static indexing only -- rule #20)
            if ((ec >> 3) == lg) {
                const int sl = ec & 7;
#pragma unroll
                for (int m = 0; m < 8; ++m)
                    if (sl == m) s[m] = -1.f;   // sigmoid in (0,1) -> excluded
            }
        }
        const float inv = 1.f / ssum;
        out_g  [(size_t)(tok0 + tt) * TOPK + lg] = vsel * inv;
        out_idx[(size_t)(tok0 + tt) * TOPK + lg] = (float)esel;
    }
}

extern "C" void kernel_launch(void* const* d_in, const int* in_sizes, int n_in,
                              void* d_out, int out_size, void* d_ws, size_t ws_size,
                              hipStream_t stream) {
    const float* x = (const float*)d_in[0];
    const float* W = (const float*)d_in[1];
    const float* b = (const float*)d_in[2];
    // d_in[3] is k (==8), compile-time constant here.
    float* out = (float*)d_out;
    gate_kernel<<<NTOK / TOKPB, THREADS, 0, stream>>>(x, W, b, out);
}